// Round 2
// baseline (1149.579 us; speedup 1.0000x reference)
//
#include <hip/hip_runtime.h>
#include <hip/hip_bf16.h>
#include <stdint.h>

// MoE block, fp32 in/out, bf16 MFMA internally. B=8 S=4096 D=512 E=16 K=2 M=1024.
// Pipeline: init -> convert x->bf16 -> gating(fp32) -> offsets -> scatter ->
// weight transpose+convert -> grouped dual-GEMM1 (silu fuse) ->
// GEMM2 passA (k=0, store fp32) -> GEMM2 passB (k=1, add fp32).

typedef __bf16 bf16x8 __attribute__((ext_vector_type(8)));
typedef float floatx4 __attribute__((ext_vector_type(4)));
typedef short short8 __attribute__((ext_vector_type(8)));

#define NTOK 32768
#define CAP 69632  // 65536 slots + 32 buckets * 128 pad

// ws layout (bytes)
#define O_XB 0u
#define O_W0T 33554432u
#define O_W1T 50331648u
#define O_WOT 67108864u
#define O_HB 83886080u
#define O_STOK 226492416u
#define O_SW 226770944u
#define O_TE 227049472u
#define O_TW 227311616u
#define O_META 227573760u
#define WS_NEED 227574784u
// meta ints: [0..31] counts, [32..63] cursors, [64..96] start(33),
//            [97..129] t1base(33), [130..146] t2A(17), [147..163] t2B(17)

__device__ __forceinline__ unsigned short f2bf(float f) {
  unsigned int u = __float_as_uint(f);
  u += 0x7FFFu + ((u >> 16) & 1u);
  return (unsigned short)(u >> 16);
}
__device__ __forceinline__ void async16(void* lds, const void* g) {
  __builtin_amdgcn_global_load_lds(
      (const __attribute__((address_space(1))) void*)g,
      (__attribute__((address_space(3))) void*)lds, 16, 0, 0);
}

__global__ void init_kernel(int* slot_token, float* slot_weight, int* meta) {
  int i = blockIdx.x * 256 + threadIdx.x;
  if (i < CAP) { slot_token[i] = 0; slot_weight[i] = 0.f; }
  if (i < 164) meta[i] = 0;
}

// x fp32 -> bf16, 8 elements/thread.
__global__ __launch_bounds__(256) void convert_x_kernel(
    const float* __restrict__ x, unsigned short* __restrict__ xb) {
  const size_t i = ((size_t)blockIdx.x * 256 + threadIdx.x) * 8;
  float4 a = *(const float4*)&x[i];
  float4 b = *(const float4*)&x[i + 4];
  short8 o;
  o[0] = f2bf(a.x); o[1] = f2bf(a.y); o[2] = f2bf(a.z); o[3] = f2bf(a.w);
  o[4] = f2bf(b.x); o[5] = f2bf(b.y); o[6] = f2bf(b.z); o[7] = f2bf(b.w);
  *(short8*)&xb[i] = o;
}

// fp32 gating: wave per token. 4 waves/block.
__global__ __launch_bounds__(256) void gating_kernel(
    const float* __restrict__ x, const float* __restrict__ wg,
    int* __restrict__ meta, int2* __restrict__ tok_e, float2* __restrict__ tok_w) {
  __shared__ __align__(16) float swg[512 * 16];
  const int tid = threadIdx.x;
#pragma unroll
  for (int p = 0; p < 8; ++p)
    ((float4*)swg)[tid + p * 256] = ((const float4*)wg)[tid + p * 256];
  __syncthreads();
  const int lane = tid & 63, wv = tid >> 6;
  const int t = blockIdx.x * 4 + wv;
  float acc[16];
#pragma unroll
  for (int e = 0; e < 16; ++e) acc[e] = 0.f;
#pragma unroll
  for (int i = 0; i < 8; ++i) {
    const int d = i * 64 + lane;
    const float xv = x[(size_t)t * 512 + d];
#pragma unroll
    for (int e = 0; e < 16; ++e) acc[e] += xv * swg[d * 16 + e];
  }
#pragma unroll
  for (int off = 32; off >= 1; off >>= 1) {
#pragma unroll
    for (int e = 0; e < 16; ++e) acc[e] += __shfl_xor(acc[e], off, 64);
  }
  if (lane == 0) {
    int e0 = 0; float v0 = acc[0];
    for (int e = 1; e < 16; ++e) if (acc[e] > v0) { v0 = acc[e]; e0 = e; }
    int e1 = (e0 == 0) ? 1 : 0; float v1 = acc[e1];
    for (int e = 0; e < 16; ++e) if (e != e0 && acc[e] > v1) { v1 = acc[e]; e1 = e; }
    const float p1 = __expf(v1 - v0);
    const float s = 1.f + p1;
    tok_e[t] = make_int2(e0, e1);
    tok_w[t] = make_float2(1.f / s, p1 / s);
    atomicAdd(&meta[e0 * 2], 1);
    atomicAdd(&meta[e1 * 2 + 1], 1);
  }
}

__global__ void offsets_kernel(int* meta) {
  if (threadIdx.x != 0 || blockIdx.x != 0) return;
  int s = 0; meta[64] = 0;
  for (int b = 0; b < 32; ++b) { s += (meta[b] + 127) & ~127; meta[64 + b + 1] = s; }
  int t = 0; meta[97] = 0;
  for (int b = 0; b < 32; ++b) { t += ((meta[b] + 127) >> 7) * 8; meta[97 + b + 1] = t; }
  int ta = 0; meta[130] = 0;
  for (int i = 0; i < 16; ++i) { ta += ((meta[2 * i] + 127) >> 7) * 4; meta[130 + i + 1] = ta; }
  int tb = 0; meta[147] = 0;
  for (int i = 0; i < 16; ++i) { tb += ((meta[2 * i + 1] + 127) >> 7) * 4; meta[147 + i + 1] = tb; }
}

__global__ void scatter_kernel(const int2* __restrict__ tok_e, const float2* __restrict__ tok_w,
                               int* __restrict__ slot_token, float* __restrict__ slot_weight,
                               int* __restrict__ meta) {
  const int t = blockIdx.x * 256 + threadIdx.x;
  if (t >= NTOK) return;
  const int2 e = tok_e[t];
  const float2 wv = tok_w[t];
  const int b0 = e.x * 2;
  const int s0 = meta[64 + b0] + atomicAdd(&meta[32 + b0], 1);
  slot_token[s0] = t; slot_weight[s0] = wv.x;
  const int b1 = e.y * 2 + 1;
  const int s1 = meta[64 + b1] + atomicAdd(&meta[32 + b1], 1);
  slot_token[s1] = t; slot_weight[s1] = wv.y;
}

// Transpose + fp32->bf16 convert per-expert weights to k-contiguous layout.
// z = tensor*16 + e. t0: w0[e] 512x1024 -> w0t[e] 1024x512 ; t1 same for w1 ;
// t2: wo[e] 1024x512 -> wot[e] 512x1024.
__global__ __launch_bounds__(256) void transpose_kernel(
    const float* __restrict__ w0, const float* __restrict__ w1,
    const float* __restrict__ wo, unsigned short* __restrict__ w0t,
    unsigned short* __restrict__ w1t, unsigned short* __restrict__ wot) {
  __shared__ __align__(16) unsigned short tile[64][72];
  const int tensor = blockIdx.z >> 4, e = blockIdx.z & 15;
  const float* src; unsigned short* dst; int R, C;
  if (tensor == 0) { src = w0; dst = w0t; R = 512; C = 1024; }
  else if (tensor == 1) { src = w1; dst = w1t; R = 512; C = 1024; }
  else { src = wo; dst = wot; R = 1024; C = 512; }
  src += (size_t)e * 524288; dst += (size_t)e * 524288;
  const int r0 = blockIdx.y * 64, c0 = blockIdx.x * 64;
  if (r0 >= R || c0 >= C) return;
  const int tid = threadIdx.x;
#pragma unroll
  for (int p = 0; p < 4; ++p) {
    const int flat = tid + p * 256;  // 0..1023
    const int r = flat >> 4, c4 = (flat & 15) * 4;
    float4 v = *(const float4*)&src[(size_t)(r0 + r) * C + c0 + c4];
    tile[r][c4 + 0] = f2bf(v.x); tile[r][c4 + 1] = f2bf(v.y);
    tile[r][c4 + 2] = f2bf(v.z); tile[r][c4 + 3] = f2bf(v.w);
  }
  __syncthreads();
#pragma unroll
  for (int p = 0; p < 2; ++p) {
    const int flat = tid + p * 256;
    const int rr = flat >> 3, cc = (flat & 7) * 8;
    short8 o;
#pragma unroll
    for (int j = 0; j < 8; ++j) o[j] = (short)tile[cc + j][rr];
    *(short8*)&dst[(size_t)(c0 + rr) * R + r0 + cc] = o;
  }
}

// GEMM1: hb[slot, m] = silu(x[tok]@w0[e])[m] * (x[tok]@w1[e])[m], 128x128 tiles.
__global__ __launch_bounds__(256, 2) void gemm1_kernel(
    const unsigned short* __restrict__ xb, const unsigned short* __restrict__ w0t,
    const unsigned short* __restrict__ w1t, unsigned short* __restrict__ hb,
    const int* __restrict__ slot_token, const int* __restrict__ meta) {
  __shared__ __align__(16) unsigned short ldsA[128 * 32];
  __shared__ __align__(16) unsigned short ldsB0[128 * 32];
  __shared__ __align__(16) unsigned short ldsB1[128 * 32];
  const int tid = threadIdx.x, lane = tid & 63, wv = tid >> 6;
  const int wm = wv >> 1, wn = wv & 1;
  const int total = meta[129];
  const int rA = wv * 16 + (lane >> 2);
  const int cb = (lane & 3) * 16;
  char* dA0 = (char*)ldsA + wv * 1024 + lane * 16;
  char* dA1 = dA0 + 4096;
  char* dB00 = (char*)ldsB0 + wv * 1024 + lane * 16;
  char* dB01 = dB00 + 4096;
  char* dB10 = (char*)ldsB1 + wv * 1024 + lane * 16;
  char* dB11 = dB10 + 4096;
  const int ml = lane & 15, kq = (lane >> 4) * 8;
  const unsigned short* pA = &ldsA[(wm * 64 + ml) * 32 + kq];
  const unsigned short* pB0 = &ldsB0[(wn * 64 + ml) * 32 + kq];
  const unsigned short* pB1 = &ldsB1[(wn * 64 + ml) * 32 + kq];

  for (int w = blockIdx.x; w < total; w += gridDim.x) {
    int b = 0;
    while (b < 31 && w >= meta[97 + b + 1]) ++b;
    const int local = w - meta[97 + b];
    const int mt = local >> 3, nt = local & 7;
    const int e = b >> 1;
    const int slot0 = meta[64 + b] + mt * 128;
    const int n0 = nt * 128;
    const int tok0 = slot_token[slot0 + rA];
    const int tok1 = slot_token[slot0 + 64 + rA];
    const char* gA0 = (const char*)(xb + (size_t)tok0 * 512) + cb;
    const char* gA1 = (const char*)(xb + (size_t)tok1 * 512) + cb;
    const char* gB00 = (const char*)(w0t + ((size_t)e * 1024 + n0 + rA) * 512) + cb;
    const char* gB01 = gB00 + 65536;
    const char* gB10 = (const char*)(w1t + ((size_t)e * 1024 + n0 + rA) * 512) + cb;
    const char* gB11 = gB10 + 65536;
    floatx4 acc0[4][4], acc1[4][4];
#pragma unroll
    for (int i = 0; i < 4; ++i)
#pragma unroll
      for (int j = 0; j < 4; ++j) {
        acc0[i][j] = (floatx4){0.f, 0.f, 0.f, 0.f};
        acc1[i][j] = (floatx4){0.f, 0.f, 0.f, 0.f};
      }
#pragma unroll 1
    for (int kt = 0; kt < 16; ++kt) {
      __syncthreads();
      const int ko = kt * 64;
      async16(dA0, gA0 + ko); async16(dA1, gA1 + ko);
      async16(dB00, gB00 + ko); async16(dB01, gB01 + ko);
      async16(dB10, gB10 + ko); async16(dB11, gB11 + ko);
      __syncthreads();
      bf16x8 aV[4], b0V[4], b1V[4];
#pragma unroll
      for (int mi = 0; mi < 4; ++mi) aV[mi] = *(const bf16x8*)(pA + mi * 512);
#pragma unroll
      for (int ni = 0; ni < 4; ++ni) {
        b0V[ni] = *(const bf16x8*)(pB0 + ni * 512);
        b1V[ni] = *(const bf16x8*)(pB1 + ni * 512);
      }
#pragma unroll
      for (int mi = 0; mi < 4; ++mi)
#pragma unroll
        for (int ni = 0; ni < 4; ++ni) {
          acc0[mi][ni] = __builtin_amdgcn_mfma_f32_16x16x32_bf16(aV[mi], b0V[ni], acc0[mi][ni], 0, 0, 0);
          acc1[mi][ni] = __builtin_amdgcn_mfma_f32_16x16x32_bf16(aV[mi], b1V[ni], acc1[mi][ni], 0, 0, 0);
        }
    }
    const int rb = slot0 + wm * 64 + (lane >> 4) * 4;
    const int cbase = n0 + wn * 64 + ml;
#pragma unroll
    for (int mi = 0; mi < 4; ++mi)
#pragma unroll
      for (int ni = 0; ni < 4; ++ni) {
#pragma unroll
        for (int r = 0; r < 4; ++r) {
          const float h0 = acc0[mi][ni][r];
          const float hv = h0 * acc1[mi][ni][r] / (1.f + __expf(-h0));
          hb[(size_t)(rb + mi * 16 + r) * 1024 + cbase + ni * 16] = f2bf(hv);
        }
      }
  }
}

// GEMM2: out[tok] (+)= w_slot * (hb[slot] @ wo[e]); kSel=0 store, kSel=1 add. fp32 out.
__global__ __launch_bounds__(256, 2) void gemm2_kernel(
    const unsigned short* __restrict__ hb, const unsigned short* __restrict__ wot,
    float* __restrict__ out, const int* __restrict__ slot_token,
    const float* __restrict__ slot_weight, const int* __restrict__ meta, const int kSel) {
  __shared__ __align__(16) unsigned short ldsA[128 * 32];
  __shared__ __align__(16) unsigned short ldsB[128 * 32];
  const int tid = threadIdx.x, lane = tid & 63, wv = tid >> 6;
  const int wm = wv >> 1, wn = wv & 1;
  const int baseOff = kSel ? 147 : 130;
  const int total = meta[baseOff + 16];
  const int rA = wv * 16 + (lane >> 2);
  const int cb = (lane & 3) * 16;
  char* dA0 = (char*)ldsA + wv * 1024 + lane * 16;
  char* dA1 = dA0 + 4096;
  char* dB0 = (char*)ldsB + wv * 1024 + lane * 16;
  char* dB1 = dB0 + 4096;
  const int ml = lane & 15, kq = (lane >> 4) * 8;
  const unsigned short* pA = &ldsA[(wm * 64 + ml) * 32 + kq];
  const unsigned short* pB = &ldsB[(wn * 64 + ml) * 32 + kq];

  for (int w = blockIdx.x; w < total; w += gridDim.x) {
    int i = 0;
    while (i < 15 && w >= meta[baseOff + i + 1]) ++i;
    const int b = 2 * i + kSel, e = i;
    const int local = w - meta[baseOff + i];
    const int mt = local >> 2, nt = local & 3;
    const int slot0 = meta[64 + b] + mt * 128;
    const int n0 = nt * 128;
    const int bend = meta[64 + b] + meta[b];
    const char* gA0 = (const char*)(hb + (size_t)(slot0 + rA) * 1024) + cb;
    const char* gA1 = gA0 + 64 * 2048;
    const char* gB0 = (const char*)(wot + ((size_t)e * 512 + n0 + rA) * 1024) + cb;
    const char* gB1 = gB0 + 64 * 2048;
    floatx4 acc[4][4];
#pragma unroll
    for (int a = 0; a < 4; ++a)
#pragma unroll
      for (int c = 0; c < 4; ++c) acc[a][c] = (floatx4){0.f, 0.f, 0.f, 0.f};
#pragma unroll 1
    for (int kt = 0; kt < 32; ++kt) {
      __syncthreads();
      const int ko = kt * 64;
      async16(dA0, gA0 + ko); async16(dA1, gA1 + ko);
      async16(dB0, gB0 + ko); async16(dB1, gB1 + ko);
      __syncthreads();
      bf16x8 aV[4], bV[4];
#pragma unroll
      for (int mi = 0; mi < 4; ++mi) aV[mi] = *(const bf16x8*)(pA + mi * 512);
#pragma unroll
      for (int ni = 0; ni < 4; ++ni) bV[ni] = *(const bf16x8*)(pB + ni * 512);
#pragma unroll
      for (int mi = 0; mi < 4; ++mi)
#pragma unroll
        for (int ni = 0; ni < 4; ++ni)
          acc[mi][ni] = __builtin_amdgcn_mfma_f32_16x16x32_bf16(aV[mi], bV[ni], acc[mi][ni], 0, 0, 0);
    }
    const int rb = slot0 + wm * 64 + (lane >> 4) * 4;
    const int cbase = n0 + wn * 64 + ml;
#pragma unroll
    for (int mi = 0; mi < 4; ++mi) {
#pragma unroll
      for (int r = 0; r < 4; ++r) {
        const int sl = rb + mi * 16 + r;
        if (sl < bend) {
          const int tk = slot_token[sl];
          const float wt = slot_weight[sl];
#pragma unroll
          for (int ni = 0; ni < 4; ++ni) {
            const size_t oidx = (size_t)tk * 512 + cbase + ni * 16;
            float v = acc[mi][ni][r] * wt;
            if (kSel) v += out[oidx];
            out[oidx] = v;
          }
        }
      }
    }
  }
}

extern "C" void kernel_launch(void* const* d_in, const int* in_sizes, int n_in,
                              void* d_out, int out_size, void* d_ws, size_t ws_size,
                              hipStream_t stream) {
  const float* x = (const float*)d_in[0];
  const float* wg = (const float*)d_in[1];
  const float* w0 = (const float*)d_in[2];
  const float* w1 = (const float*)d_in[3];
  const float* wo = (const float*)d_in[4];
  float* out = (float*)d_out;
  char* ws = (char*)d_ws;
  if (ws_size < (size_t)WS_NEED) return;  // need ~217 MB scratch
  unsigned short* xb = (unsigned short*)(ws + O_XB);
  unsigned short* w0t = (unsigned short*)(ws + O_W0T);
  unsigned short* w1t = (unsigned short*)(ws + O_W1T);
  unsigned short* wot = (unsigned short*)(ws + O_WOT);
  unsigned short* hb = (unsigned short*)(ws + O_HB);
  int* slot_token = (int*)(ws + O_STOK);
  float* slot_weight = (float*)(ws + O_SW);
  int2* tok_e = (int2*)(ws + O_TE);
  float2* tok_w = (float2*)(ws + O_TW);
  int* meta = (int*)(ws + O_META);

  init_kernel<<<(CAP + 255) / 256, 256, 0, stream>>>(slot_token, slot_weight, meta);
  convert_x_kernel<<<NTOK * 512 / 2048, 256, 0, stream>>>(x, xb);
  gating_kernel<<<NTOK / 4, 256, 0, stream>>>(x, wg, meta, tok_e, tok_w);
  offsets_kernel<<<1, 1, 0, stream>>>(meta);
  scatter_kernel<<<NTOK / 256, 256, 0, stream>>>(tok_e, tok_w, slot_token, slot_weight, meta);
  transpose_kernel<<<dim3(16, 16, 48), 256, 0, stream>>>(w0, w1, wo, w0t, w1t, wot);
  gemm1_kernel<<<4096, 256, 0, stream>>>(xb, w0t, w1t, hb, slot_token, meta);
  gemm2_kernel<<<1024, 256, 0, stream>>>(hb, wot, out, slot_token, slot_weight, meta, 0);
  gemm2_kernel<<<1024, 256, 0, stream>>>(hb, wot, out, slot_token, slot_weight, meta, 1);
}

// Round 3
// 635.718 us; speedup vs baseline: 1.8083x; 1.8083x over previous
//
#include <hip/hip_runtime.h>
#include <hip/hip_bf16.h>
#include <stdint.h>

// MoE block, fp32 in/out, bf16 MFMA internally. B=8 S=4096 D=512 E=16 K=2 M=1024.
// Pipeline: init -> convert x->bf16 -> gating(fp32, register-resident wg) ->
// offsets -> scatter (block-local ranks) -> weight transpose+convert ->
// grouped dual-GEMM1 (silu fuse) -> GEMM2 passA (store) -> GEMM2 passB (add).

typedef __bf16 bf16x8 __attribute__((ext_vector_type(8)));
typedef float floatx4 __attribute__((ext_vector_type(4)));
typedef short short8 __attribute__((ext_vector_type(8)));

#define NTOK 32768
#define CAP 69632  // 65536 slots + 32 buckets * 128 pad

// ws layout (bytes)
#define O_XB 0u
#define O_W0T 33554432u
#define O_W1T 50331648u
#define O_WOT 67108864u
#define O_HB 83886080u
#define O_STOK 226492416u
#define O_SW 226770944u
#define O_TE 227049472u
#define O_TW 227311616u
#define O_META 227573760u
#define WS_NEED 227574784u
// meta ints: [0..31] counts, [32..63] cursors, [64..96] start(33),
//            [97..129] t1base(33), [130..146] t2A(17), [147..163] t2B(17)

__device__ __forceinline__ unsigned short f2bf(float f) {
  unsigned int u = __float_as_uint(f);
  u += 0x7FFFu + ((u >> 16) & 1u);
  return (unsigned short)(u >> 16);
}
__device__ __forceinline__ void async16(void* lds, const void* g) {
  __builtin_amdgcn_global_load_lds(
      (const __attribute__((address_space(1))) void*)g,
      (__attribute__((address_space(3))) void*)lds, 16, 0, 0);
}

__global__ void init_kernel(int* slot_token, float* slot_weight, int* meta) {
  int i = blockIdx.x * 256 + threadIdx.x;
  if (i < CAP) { slot_token[i] = 0; slot_weight[i] = 0.f; }
  if (i < 164) meta[i] = 0;
}

// x fp32 -> bf16, 8 elements/thread.
__global__ __launch_bounds__(256) void convert_x_kernel(
    const float* __restrict__ x, unsigned short* __restrict__ xb) {
  const size_t i = ((size_t)blockIdx.x * 256 + threadIdx.x) * 8;
  float4 a = *(const float4*)&x[i];
  float4 b = *(const float4*)&x[i + 4];
  short8 o;
  o[0] = f2bf(a.x); o[1] = f2bf(a.y); o[2] = f2bf(a.z); o[3] = f2bf(a.w);
  o[4] = f2bf(b.x); o[5] = f2bf(b.y); o[6] = f2bf(b.z); o[7] = f2bf(b.w);
  *(short8*)&xb[i] = o;
}

// fp32 gating v2: wave per token, wg register-resident (128 VGPR/lane),
// folding butterfly reduction, wave-level top-2, LDS histogram.
__global__ __launch_bounds__(256, 2) void gating_kernel(
    const float* __restrict__ x, const float* __restrict__ wg,
    int* __restrict__ meta, int2* __restrict__ tok_e, float2* __restrict__ tok_w) {
  __shared__ int hist[32];
  const int tid = threadIdx.x, lane = tid & 63, wv = tid >> 6;
  if (tid < 32) hist[tid] = 0;
  // wreg[i][e] = wg[(i*64+lane)*16 + e] : this lane's d-slice of wg.
  float wreg[8][16];
#pragma unroll
  for (int i = 0; i < 8; ++i) {
#pragma unroll
    for (int q = 0; q < 4; ++q) {
      float4 v = *(const float4*)&wg[(size_t)(i * 64 + lane) * 16 + q * 4];
      wreg[i][q * 4 + 0] = v.x; wreg[i][q * 4 + 1] = v.y;
      wreg[i][q * 4 + 2] = v.z; wreg[i][q * 4 + 3] = v.w;
    }
  }
  __syncthreads();
  // expert owned by this lane after the fold (bits 5..2 of lane):
  const int my_e = ((lane >> 5) & 1) * 8 + ((lane >> 4) & 1) * 4 +
                   ((lane >> 3) & 1) * 2 + ((lane >> 2) & 1);
  const int wave_id = blockIdx.x * 4 + wv;  // 2048 waves
  for (int t = wave_id; t < NTOK; t += 2048) {
    float xs[8];
#pragma unroll
    for (int i = 0; i < 8; ++i) xs[i] = x[(size_t)t * 512 + i * 64 + lane];
    float acc[16];
#pragma unroll
    for (int e = 0; e < 16; ++e) acc[e] = 0.f;
#pragma unroll
    for (int i = 0; i < 8; ++i)
#pragma unroll
      for (int e = 0; e < 16; ++e) acc[e] += xs[i] * wreg[i][e];
    // fold: 16 vals -> 1 val/lane, experts spread over lane bits 5,4,3,2.
    float a8[8];
#pragma unroll
    for (int e = 0; e < 8; ++e) {
      float s0 = acc[e] + __shfl_xor(acc[e], 32, 64);
      float s1 = acc[e + 8] + __shfl_xor(acc[e + 8], 32, 64);
      a8[e] = (lane & 32) ? s1 : s0;
    }
    float a4[4];
#pragma unroll
    for (int e = 0; e < 4; ++e) {
      float s0 = a8[e] + __shfl_xor(a8[e], 16, 64);
      float s1 = a8[e + 4] + __shfl_xor(a8[e + 4], 16, 64);
      a4[e] = (lane & 16) ? s1 : s0;
    }
    float a2[2];
#pragma unroll
    for (int e = 0; e < 2; ++e) {
      float s0 = a4[e] + __shfl_xor(a4[e], 8, 64);
      float s1 = a4[e + 2] + __shfl_xor(a4[e + 2], 8, 64);
      a2[e] = (lane & 8) ? s1 : s0;
    }
    float s0 = a2[0] + __shfl_xor(a2[0], 4, 64);
    float s1 = a2[1] + __shfl_xor(a2[1], 4, 64);
    float a1 = (lane & 4) ? s1 : s0;
    a1 += __shfl_xor(a1, 2, 64);
    a1 += __shfl_xor(a1, 1, 64);
    // wave top-2 with lowest-index tiebreak.
    float m1 = a1;
#pragma unroll
    for (int s = 32; s >= 1; s >>= 1) m1 = fmaxf(m1, __shfl_xor(m1, s, 64));
    int c1 = (a1 == m1) ? my_e : 999;
#pragma unroll
    for (int s = 32; s >= 1; s >>= 1) c1 = min(c1, __shfl_xor(c1, s, 64));
    const float av = (my_e == c1) ? -3.4e38f : a1;
    float m2 = av;
#pragma unroll
    for (int s = 32; s >= 1; s >>= 1) m2 = fmaxf(m2, __shfl_xor(m2, s, 64));
    int c2 = (av == m2) ? my_e : 999;
#pragma unroll
    for (int s = 32; s >= 1; s >>= 1) c2 = min(c2, __shfl_xor(c2, s, 64));
    if (lane == 0) {
      const float p1 = __expf(m2 - m1);
      const float sm = 1.f + p1;
      tok_e[t] = make_int2(c1, c2);
      tok_w[t] = make_float2(1.f / sm, p1 / sm);
      atomicAdd(&hist[c1 * 2], 1);
      atomicAdd(&hist[c2 * 2 + 1], 1);
    }
  }
  __syncthreads();
  if (tid < 32 && hist[tid] > 0) atomicAdd(&meta[tid], hist[tid]);
}

__global__ void offsets_kernel(int* meta) {
  if (threadIdx.x != 0 || blockIdx.x != 0) return;
  int s = 0; meta[64] = 0;
  for (int b = 0; b < 32; ++b) { s += (meta[b] + 127) & ~127; meta[64 + b + 1] = s; }
  int t = 0; meta[97] = 0;
  for (int b = 0; b < 32; ++b) { t += ((meta[b] + 127) >> 7) * 8; meta[97 + b + 1] = t; }
  int ta = 0; meta[130] = 0;
  for (int i = 0; i < 16; ++i) { ta += ((meta[2 * i] + 127) >> 7) * 4; meta[130 + i + 1] = ta; }
  int tb = 0; meta[147] = 0;
  for (int i = 0; i < 16; ++i) { tb += ((meta[2 * i + 1] + 127) >> 7) * 4; meta[147 + i + 1] = tb; }
}

// scatter v2: block-local histogram + one global atomic per bucket per block.
__global__ __launch_bounds__(256) void scatter_kernel(
    const int2* __restrict__ tok_e, const float2* __restrict__ tok_w,
    int* __restrict__ slot_token, float* __restrict__ slot_weight,
    int* __restrict__ meta) {
  __shared__ int hist[32], base[32], lcur[32];
  const int tid = threadIdx.x;
  if (tid < 32) { hist[tid] = 0; lcur[tid] = 0; }
  __syncthreads();
  const int t = blockIdx.x * 256 + tid;
  const int2 e = tok_e[t];
  const float2 wv = tok_w[t];
  const int b0 = e.x * 2, b1 = e.y * 2 + 1;
  atomicAdd(&hist[b0], 1);
  atomicAdd(&hist[b1], 1);
  __syncthreads();
  if (tid < 32 && hist[tid] > 0) base[tid] = atomicAdd(&meta[32 + tid], hist[tid]);
  __syncthreads();
  const int r0 = atomicAdd(&lcur[b0], 1);
  const int s0 = meta[64 + b0] + base[b0] + r0;
  slot_token[s0] = t; slot_weight[s0] = wv.x;
  const int r1 = atomicAdd(&lcur[b1], 1);
  const int s1 = meta[64 + b1] + base[b1] + r1;
  slot_token[s1] = t; slot_weight[s1] = wv.y;
}

// Transpose + fp32->bf16 convert per-expert weights to k-contiguous layout.
// z = tensor*16 + e. t0: w0[e] 512x1024 -> w0t[e] 1024x512 ; t1 same for w1 ;
// t2: wo[e] 1024x512 -> wot[e] 512x1024.
__global__ __launch_bounds__(256) void transpose_kernel(
    const float* __restrict__ w0, const float* __restrict__ w1,
    const float* __restrict__ wo, unsigned short* __restrict__ w0t,
    unsigned short* __restrict__ w1t, unsigned short* __restrict__ wot) {
  __shared__ __align__(16) unsigned short tile[64][72];
  const int tensor = blockIdx.z >> 4, e = blockIdx.z & 15;
  const float* src; unsigned short* dst; int R, C;
  if (tensor == 0) { src = w0; dst = w0t; R = 512; C = 1024; }
  else if (tensor == 1) { src = w1; dst = w1t; R = 512; C = 1024; }
  else { src = wo; dst = wot; R = 1024; C = 512; }
  src += (size_t)e * 524288; dst += (size_t)e * 524288;
  const int r0 = blockIdx.y * 64, c0 = blockIdx.x * 64;
  if (r0 >= R || c0 >= C) return;
  const int tid = threadIdx.x;
#pragma unroll
  for (int p = 0; p < 4; ++p) {
    const int flat = tid + p * 256;  // 0..1023
    const int r = flat >> 4, c4 = (flat & 15) * 4;
    float4 v = *(const float4*)&src[(size_t)(r0 + r) * C + c0 + c4];
    tile[r][c4 + 0] = f2bf(v.x); tile[r][c4 + 1] = f2bf(v.y);
    tile[r][c4 + 2] = f2bf(v.z); tile[r][c4 + 3] = f2bf(v.w);
  }
  __syncthreads();
#pragma unroll
  for (int p = 0; p < 2; ++p) {
    const int flat = tid + p * 256;
    const int rr = flat >> 3, cc = (flat & 7) * 8;
    short8 o;
#pragma unroll
    for (int j = 0; j < 8; ++j) o[j] = (short)tile[cc + j][rr];
    *(short8*)&dst[(size_t)(c0 + rr) * R + r0 + cc] = o;
  }
}

// GEMM1: hb[slot, m] = silu(x[tok]@w0[e])[m] * (x[tok]@w1[e])[m], 128x128 tiles.
__global__ __launch_bounds__(256, 2) void gemm1_kernel(
    const unsigned short* __restrict__ xb, const unsigned short* __restrict__ w0t,
    const unsigned short* __restrict__ w1t, unsigned short* __restrict__ hb,
    const int* __restrict__ slot_token, const int* __restrict__ meta) {
  __shared__ __align__(16) unsigned short ldsA[128 * 32];
  __shared__ __align__(16) unsigned short ldsB0[128 * 32];
  __shared__ __align__(16) unsigned short ldsB1[128 * 32];
  const int tid = threadIdx.x, lane = tid & 63, wv = tid >> 6;
  const int wm = wv >> 1, wn = wv & 1;
  const int total = meta[129];
  const int rA = wv * 16 + (lane >> 2);
  const int cb = (lane & 3) * 16;
  char* dA0 = (char*)ldsA + wv * 1024 + lane * 16;
  char* dA1 = dA0 + 4096;
  char* dB00 = (char*)ldsB0 + wv * 1024 + lane * 16;
  char* dB01 = dB00 + 4096;
  char* dB10 = (char*)ldsB1 + wv * 1024 + lane * 16;
  char* dB11 = dB10 + 4096;
  const int ml = lane & 15, kq = (lane >> 4) * 8;
  const unsigned short* pA = &ldsA[(wm * 64 + ml) * 32 + kq];
  const unsigned short* pB0 = &ldsB0[(wn * 64 + ml) * 32 + kq];
  const unsigned short* pB1 = &ldsB1[(wn * 64 + ml) * 32 + kq];

  for (int w = blockIdx.x; w < total; w += gridDim.x) {
    int b = 0;
    while (b < 31 && w >= meta[97 + b + 1]) ++b;
    const int local = w - meta[97 + b];
    const int mt = local >> 3, nt = local & 7;
    const int e = b >> 1;
    const int slot0 = meta[64 + b] + mt * 128;
    const int n0 = nt * 128;
    const int tok0 = slot_token[slot0 + rA];
    const int tok1 = slot_token[slot0 + 64 + rA];
    const char* gA0 = (const char*)(xb + (size_t)tok0 * 512) + cb;
    const char* gA1 = (const char*)(xb + (size_t)tok1 * 512) + cb;
    const char* gB00 = (const char*)(w0t + ((size_t)e * 1024 + n0 + rA) * 512) + cb;
    const char* gB01 = gB00 + 65536;
    const char* gB10 = (const char*)(w1t + ((size_t)e * 1024 + n0 + rA) * 512) + cb;
    const char* gB11 = gB10 + 65536;
    floatx4 acc0[4][4], acc1[4][4];
#pragma unroll
    for (int i = 0; i < 4; ++i)
#pragma unroll
      for (int j = 0; j < 4; ++j) {
        acc0[i][j] = (floatx4){0.f, 0.f, 0.f, 0.f};
        acc1[i][j] = (floatx4){0.f, 0.f, 0.f, 0.f};
      }
#pragma unroll 1
    for (int kt = 0; kt < 16; ++kt) {
      __syncthreads();
      const int ko = kt * 64;
      async16(dA0, gA0 + ko); async16(dA1, gA1 + ko);
      async16(dB00, gB00 + ko); async16(dB01, gB01 + ko);
      async16(dB10, gB10 + ko); async16(dB11, gB11 + ko);
      __syncthreads();
      bf16x8 aV[4], b0V[4], b1V[4];
#pragma unroll
      for (int mi = 0; mi < 4; ++mi) aV[mi] = *(const bf16x8*)(pA + mi * 512);
#pragma unroll
      for (int ni = 0; ni < 4; ++ni) {
        b0V[ni] = *(const bf16x8*)(pB0 + ni * 512);
        b1V[ni] = *(const bf16x8*)(pB1 + ni * 512);
      }
#pragma unroll
      for (int mi = 0; mi < 4; ++mi)
#pragma unroll
        for (int ni = 0; ni < 4; ++ni) {
          acc0[mi][ni] = __builtin_amdgcn_mfma_f32_16x16x32_bf16(aV[mi], b0V[ni], acc0[mi][ni], 0, 0, 0);
          acc1[mi][ni] = __builtin_amdgcn_mfma_f32_16x16x32_bf16(aV[mi], b1V[ni], acc1[mi][ni], 0, 0, 0);
        }
    }
    const int rb = slot0 + wm * 64 + (lane >> 4) * 4;
    const int cbase = n0 + wn * 64 + ml;
#pragma unroll
    for (int mi = 0; mi < 4; ++mi)
#pragma unroll
      for (int ni = 0; ni < 4; ++ni) {
#pragma unroll
        for (int r = 0; r < 4; ++r) {
          const float h0 = acc0[mi][ni][r];
          const float hv = h0 * acc1[mi][ni][r] / (1.f + __expf(-h0));
          hb[(size_t)(rb + mi * 16 + r) * 1024 + cbase + ni * 16] = f2bf(hv);
        }
      }
  }
}

// GEMM2: out[tok] (+)= w_slot * (hb[slot] @ wo[e]); kSel=0 store, kSel=1 add. fp32 out.
__global__ __launch_bounds__(256, 2) void gemm2_kernel(
    const unsigned short* __restrict__ hb, const unsigned short* __restrict__ wot,
    float* __restrict__ out, const int* __restrict__ slot_token,
    const float* __restrict__ slot_weight, const int* __restrict__ meta, const int kSel) {
  __shared__ __align__(16) unsigned short ldsA[128 * 32];
  __shared__ __align__(16) unsigned short ldsB[128 * 32];
  const int tid = threadIdx.x, lane = tid & 63, wv = tid >> 6;
  const int wm = wv >> 1, wn = wv & 1;
  const int baseOff = kSel ? 147 : 130;
  const int total = meta[baseOff + 16];
  const int rA = wv * 16 + (lane >> 2);
  const int cb = (lane & 3) * 16;
  char* dA0 = (char*)ldsA + wv * 1024 + lane * 16;
  char* dA1 = dA0 + 4096;
  char* dB0 = (char*)ldsB + wv * 1024 + lane * 16;
  char* dB1 = dB0 + 4096;
  const int ml = lane & 15, kq = (lane >> 4) * 8;
  const unsigned short* pA = &ldsA[(wm * 64 + ml) * 32 + kq];
  const unsigned short* pB = &ldsB[(wn * 64 + ml) * 32 + kq];

  for (int w = blockIdx.x; w < total; w += gridDim.x) {
    int i = 0;
    while (i < 15 && w >= meta[baseOff + i + 1]) ++i;
    const int b = 2 * i + kSel, e = i;
    const int local = w - meta[baseOff + i];
    const int mt = local >> 2, nt = local & 3;
    const int slot0 = meta[64 + b] + mt * 128;
    const int n0 = nt * 128;
    const int bend = meta[64 + b] + meta[b];
    const char* gA0 = (const char*)(hb + (size_t)(slot0 + rA) * 1024) + cb;
    const char* gA1 = gA0 + 64 * 2048;
    const char* gB0 = (const char*)(wot + ((size_t)e * 512 + n0 + rA) * 1024) + cb;
    const char* gB1 = gB0 + 64 * 2048;
    floatx4 acc[4][4];
#pragma unroll
    for (int a = 0; a < 4; ++a)
#pragma unroll
      for (int c = 0; c < 4; ++c) acc[a][c] = (floatx4){0.f, 0.f, 0.f, 0.f};
#pragma unroll 1
    for (int kt = 0; kt < 32; ++kt) {
      __syncthreads();
      const int ko = kt * 64;
      async16(dA0, gA0 + ko); async16(dA1, gA1 + ko);
      async16(dB0, gB0 + ko); async16(dB1, gB1 + ko);
      __syncthreads();
      bf16x8 aV[4], bV[4];
#pragma unroll
      for (int mi = 0; mi < 4; ++mi) aV[mi] = *(const bf16x8*)(pA + mi * 512);
#pragma unroll
      for (int ni = 0; ni < 4; ++ni) bV[ni] = *(const bf16x8*)(pB + ni * 512);
#pragma unroll
      for (int mi = 0; mi < 4; ++mi)
#pragma unroll
        for (int ni = 0; ni < 4; ++ni)
          acc[mi][ni] = __builtin_amdgcn_mfma_f32_16x16x32_bf16(aV[mi], bV[ni], acc[mi][ni], 0, 0, 0);
    }
    const int rb = slot0 + wm * 64 + (lane >> 4) * 4;
    const int cbase = n0 + wn * 64 + ml;
#pragma unroll
    for (int mi = 0; mi < 4; ++mi) {
#pragma unroll
      for (int r = 0; r < 4; ++r) {
        const int sl = rb + mi * 16 + r;
        if (sl < bend) {
          const int tk = slot_token[sl];
          const float wt = slot_weight[sl];
#pragma unroll
          for (int ni = 0; ni < 4; ++ni) {
            const size_t oidx = (size_t)tk * 512 + cbase + ni * 16;
            float v = acc[mi][ni][r] * wt;
            if (kSel) v += out[oidx];
            out[oidx] = v;
          }
        }
      }
    }
  }
}

extern "C" void kernel_launch(void* const* d_in, const int* in_sizes, int n_in,
                              void* d_out, int out_size, void* d_ws, size_t ws_size,
                              hipStream_t stream) {
  const float* x = (const float*)d_in[0];
  const float* wg = (const float*)d_in[1];
  const float* w0 = (const float*)d_in[2];
  const float* w1 = (const float*)d_in[3];
  const float* wo = (const float*)d_in[4];
  float* out = (float*)d_out;
  char* ws = (char*)d_ws;
  if (ws_size < (size_t)WS_NEED) return;  // need ~217 MB scratch
  unsigned short* xb = (unsigned short*)(ws + O_XB);
  unsigned short* w0t = (unsigned short*)(ws + O_W0T);
  unsigned short* w1t = (unsigned short*)(ws + O_W1T);
  unsigned short* wot = (unsigned short*)(ws + O_WOT);
  unsigned short* hb = (unsigned short*)(ws + O_HB);
  int* slot_token = (int*)(ws + O_STOK);
  float* slot_weight = (float*)(ws + O_SW);
  int2* tok_e = (int2*)(ws + O_TE);
  float2* tok_w = (float2*)(ws + O_TW);
  int* meta = (int*)(ws + O_META);

  init_kernel<<<(CAP + 255) / 256, 256, 0, stream>>>(slot_token, slot_weight, meta);
  convert_x_kernel<<<NTOK * 512 / 2048, 256, 0, stream>>>(x, xb);
  gating_kernel<<<512, 256, 0, stream>>>(x, wg, meta, tok_e, tok_w);
  offsets_kernel<<<1, 1, 0, stream>>>(meta);
  scatter_kernel<<<NTOK / 256, 256, 0, stream>>>(tok_e, tok_w, slot_token, slot_weight, meta);
  transpose_kernel<<<dim3(16, 16, 48), 256, 0, stream>>>(w0, w1, wo, w0t, w1t, wot);
  gemm1_kernel<<<4096, 256, 0, stream>>>(xb, w0t, w1t, hb, slot_token, meta);
  gemm2_kernel<<<1024, 256, 0, stream>>>(hb, wot, out, slot_token, slot_weight, meta, 0);
  gemm2_kernel<<<1024, 256, 0, stream>>>(hb, wot, out, slot_token, slot_weight, meta, 1);
}

// Round 4
// 625.568 us; speedup vs baseline: 1.8377x; 1.0162x over previous
//
#include <hip/hip_runtime.h>
#include <hip/hip_bf16.h>
#include <stdint.h>

// MoE block, fp32 in/out, bf16 MFMA internally. B=8 S=4096 D=512 E=16 K=2 M=1024.
// R4: LDS chunk-rotation swizzle in gemm1/gemm2 (kills 8-way bank conflicts on
// fragment ds_read_b128; rows r,r+2 alias at 64B stride -> rotate 16B chunks by (r>>1)&3).

typedef __bf16 bf16x8 __attribute__((ext_vector_type(8)));
typedef float floatx4 __attribute__((ext_vector_type(4)));
typedef short short8 __attribute__((ext_vector_type(8)));

#define NTOK 32768
#define CAP 69632  // 65536 slots + 32 buckets * 128 pad

// ws layout (bytes)
#define O_XB 0u
#define O_W0T 33554432u
#define O_W1T 50331648u
#define O_WOT 67108864u
#define O_HB 83886080u
#define O_STOK 226492416u
#define O_SW 226770944u
#define O_TE 227049472u
#define O_TW 227311616u
#define O_META 227573760u
#define WS_NEED 227574784u
// meta ints: [0..31] counts, [32..63] cursors, [64..96] start(33),
//            [97..129] t1base(33), [130..146] t2A(17), [147..163] t2B(17)

__device__ __forceinline__ unsigned short f2bf(float f) {
  unsigned int u = __float_as_uint(f);
  u += 0x7FFFu + ((u >> 16) & 1u);
  return (unsigned short)(u >> 16);
}
__device__ __forceinline__ void async16(void* lds, const void* g) {
  __builtin_amdgcn_global_load_lds(
      (const __attribute__((address_space(1))) void*)g,
      (__attribute__((address_space(3))) void*)lds, 16, 0, 0);
}

__global__ void init_kernel(int* slot_token, float* slot_weight, int* meta) {
  int i = blockIdx.x * 256 + threadIdx.x;
  if (i < CAP) { slot_token[i] = 0; slot_weight[i] = 0.f; }
  if (i < 164) meta[i] = 0;
}

// x fp32 -> bf16, 8 elements/thread.
__global__ __launch_bounds__(256) void convert_x_kernel(
    const float* __restrict__ x, unsigned short* __restrict__ xb) {
  const size_t i = ((size_t)blockIdx.x * 256 + threadIdx.x) * 8;
  float4 a = *(const float4*)&x[i];
  float4 b = *(const float4*)&x[i + 4];
  short8 o;
  o[0] = f2bf(a.x); o[1] = f2bf(a.y); o[2] = f2bf(a.z); o[3] = f2bf(a.w);
  o[4] = f2bf(b.x); o[5] = f2bf(b.y); o[6] = f2bf(b.z); o[7] = f2bf(b.w);
  *(short8*)&xb[i] = o;
}

// fp32 gating: wave per token, wg register-resident, folding butterfly,
// wave top-2, LDS histogram.
__global__ __launch_bounds__(256, 2) void gating_kernel(
    const float* __restrict__ x, const float* __restrict__ wg,
    int* __restrict__ meta, int2* __restrict__ tok_e, float2* __restrict__ tok_w) {
  __shared__ int hist[32];
  const int tid = threadIdx.x, lane = tid & 63, wv = tid >> 6;
  if (tid < 32) hist[tid] = 0;
  float wreg[8][16];
#pragma unroll
  for (int i = 0; i < 8; ++i) {
#pragma unroll
    for (int q = 0; q < 4; ++q) {
      float4 v = *(const float4*)&wg[(size_t)(i * 64 + lane) * 16 + q * 4];
      wreg[i][q * 4 + 0] = v.x; wreg[i][q * 4 + 1] = v.y;
      wreg[i][q * 4 + 2] = v.z; wreg[i][q * 4 + 3] = v.w;
    }
  }
  __syncthreads();
  const int my_e = ((lane >> 5) & 1) * 8 + ((lane >> 4) & 1) * 4 +
                   ((lane >> 3) & 1) * 2 + ((lane >> 2) & 1);
  const int wave_id = blockIdx.x * 4 + wv;
  for (int t = wave_id; t < NTOK; t += 2048) {
    float xs[8];
#pragma unroll
    for (int i = 0; i < 8; ++i) xs[i] = x[(size_t)t * 512 + i * 64 + lane];
    float acc[16];
#pragma unroll
    for (int e = 0; e < 16; ++e) acc[e] = 0.f;
#pragma unroll
    for (int i = 0; i < 8; ++i)
#pragma unroll
      for (int e = 0; e < 16; ++e) acc[e] += xs[i] * wreg[i][e];
    float a8[8];
#pragma unroll
    for (int e = 0; e < 8; ++e) {
      float s0 = acc[e] + __shfl_xor(acc[e], 32, 64);
      float s1 = acc[e + 8] + __shfl_xor(acc[e + 8], 32, 64);
      a8[e] = (lane & 32) ? s1 : s0;
    }
    float a4[4];
#pragma unroll
    for (int e = 0; e < 4; ++e) {
      float s0 = a8[e] + __shfl_xor(a8[e], 16, 64);
      float s1 = a8[e + 4] + __shfl_xor(a8[e + 4], 16, 64);
      a4[e] = (lane & 16) ? s1 : s0;
    }
    float a2[2];
#pragma unroll
    for (int e = 0; e < 2; ++e) {
      float s0 = a4[e] + __shfl_xor(a4[e], 8, 64);
      float s1 = a4[e + 2] + __shfl_xor(a4[e + 2], 8, 64);
      a2[e] = (lane & 8) ? s1 : s0;
    }
    float s0 = a2[0] + __shfl_xor(a2[0], 4, 64);
    float s1 = a2[1] + __shfl_xor(a2[1], 4, 64);
    float a1 = (lane & 4) ? s1 : s0;
    a1 += __shfl_xor(a1, 2, 64);
    a1 += __shfl_xor(a1, 1, 64);
    float m1 = a1;
#pragma unroll
    for (int s = 32; s >= 1; s >>= 1) m1 = fmaxf(m1, __shfl_xor(m1, s, 64));
    int c1 = (a1 == m1) ? my_e : 999;
#pragma unroll
    for (int s = 32; s >= 1; s >>= 1) c1 = min(c1, __shfl_xor(c1, s, 64));
    const float av = (my_e == c1) ? -3.4e38f : a1;
    float m2 = av;
#pragma unroll
    for (int s = 32; s >= 1; s >>= 1) m2 = fmaxf(m2, __shfl_xor(m2, s, 64));
    int c2 = (av == m2) ? my_e : 999;
#pragma unroll
    for (int s = 32; s >= 1; s >>= 1) c2 = min(c2, __shfl_xor(c2, s, 64));
    if (lane == 0) {
      const float p1 = __expf(m2 - m1);
      const float sm = 1.f + p1;
      tok_e[t] = make_int2(c1, c2);
      tok_w[t] = make_float2(1.f / sm, p1 / sm);
      atomicAdd(&hist[c1 * 2], 1);
      atomicAdd(&hist[c2 * 2 + 1], 1);
    }
  }
  __syncthreads();
  if (tid < 32 && hist[tid] > 0) atomicAdd(&meta[tid], hist[tid]);
}

__global__ void offsets_kernel(int* meta) {
  if (threadIdx.x != 0 || blockIdx.x != 0) return;
  int s = 0; meta[64] = 0;
  for (int b = 0; b < 32; ++b) { s += (meta[b] + 127) & ~127; meta[64 + b + 1] = s; }
  int t = 0; meta[97] = 0;
  for (int b = 0; b < 32; ++b) { t += ((meta[b] + 127) >> 7) * 8; meta[97 + b + 1] = t; }
  int ta = 0; meta[130] = 0;
  for (int i = 0; i < 16; ++i) { ta += ((meta[2 * i] + 127) >> 7) * 4; meta[130 + i + 1] = ta; }
  int tb = 0; meta[147] = 0;
  for (int i = 0; i < 16; ++i) { tb += ((meta[2 * i + 1] + 127) >> 7) * 4; meta[147 + i + 1] = tb; }
}

// scatter: block-local histogram + one global atomic per bucket per block.
__global__ __launch_bounds__(256) void scatter_kernel(
    const int2* __restrict__ tok_e, const float2* __restrict__ tok_w,
    int* __restrict__ slot_token, float* __restrict__ slot_weight,
    int* __restrict__ meta) {
  __shared__ int hist[32], base[32], lcur[32];
  const int tid = threadIdx.x;
  if (tid < 32) { hist[tid] = 0; lcur[tid] = 0; }
  __syncthreads();
  const int t = blockIdx.x * 256 + tid;
  const int2 e = tok_e[t];
  const float2 wv = tok_w[t];
  const int b0 = e.x * 2, b1 = e.y * 2 + 1;
  atomicAdd(&hist[b0], 1);
  atomicAdd(&hist[b1], 1);
  __syncthreads();
  if (tid < 32 && hist[tid] > 0) base[tid] = atomicAdd(&meta[32 + tid], hist[tid]);
  __syncthreads();
  const int r0 = atomicAdd(&lcur[b0], 1);
  const int s0 = meta[64 + b0] + base[b0] + r0;
  slot_token[s0] = t; slot_weight[s0] = wv.x;
  const int r1 = atomicAdd(&lcur[b1], 1);
  const int s1 = meta[64 + b1] + base[b1] + r1;
  slot_token[s1] = t; slot_weight[s1] = wv.y;
}

// Transpose + fp32->bf16 convert per-expert weights to k-contiguous layout.
__global__ __launch_bounds__(256) void transpose_kernel(
    const float* __restrict__ w0, const float* __restrict__ w1,
    const float* __restrict__ wo, unsigned short* __restrict__ w0t,
    unsigned short* __restrict__ w1t, unsigned short* __restrict__ wot) {
  __shared__ __align__(16) unsigned short tile[64][72];
  const int tensor = blockIdx.z >> 4, e = blockIdx.z & 15;
  const float* src; unsigned short* dst; int R, C;
  if (tensor == 0) { src = w0; dst = w0t; R = 512; C = 1024; }
  else if (tensor == 1) { src = w1; dst = w1t; R = 512; C = 1024; }
  else { src = wo; dst = wot; R = 1024; C = 512; }
  src += (size_t)e * 524288; dst += (size_t)e * 524288;
  const int r0 = blockIdx.y * 64, c0 = blockIdx.x * 64;
  if (r0 >= R || c0 >= C) return;
  const int tid = threadIdx.x;
#pragma unroll
  for (int p = 0; p < 4; ++p) {
    const int flat = tid + p * 256;  // 0..1023
    const int r = flat >> 4, c4 = (flat & 15) * 4;
    float4 v = *(const float4*)&src[(size_t)(r0 + r) * C + c0 + c4];
    tile[r][c4 + 0] = f2bf(v.x); tile[r][c4 + 1] = f2bf(v.y);
    tile[r][c4 + 2] = f2bf(v.z); tile[r][c4 + 3] = f2bf(v.w);
  }
  __syncthreads();
#pragma unroll
  for (int p = 0; p < 2; ++p) {
    const int flat = tid + p * 256;
    const int rr = flat >> 3, cc = (flat & 7) * 8;
    short8 o;
#pragma unroll
    for (int j = 0; j < 8; ++j) o[j] = (short)tile[cc + j][rr];
    *(short8*)&dst[(size_t)(c0 + rr) * R + r0 + cc] = o;
  }
}

// GEMM1: hb[slot, m] = silu(x@w0)*(x@w1), 128x128 tiles, swizzled LDS.
__global__ __launch_bounds__(256, 2) void gemm1_kernel(
    const unsigned short* __restrict__ xb, const unsigned short* __restrict__ w0t,
    const unsigned short* __restrict__ w1t, unsigned short* __restrict__ hb,
    const int* __restrict__ slot_token, const int* __restrict__ meta) {
  __shared__ __align__(16) unsigned short ldsA[128 * 32];
  __shared__ __align__(16) unsigned short ldsB0[128 * 32];
  __shared__ __align__(16) unsigned short ldsB1[128 * 32];
  const int tid = threadIdx.x, lane = tid & 63, wv = tid >> 6;
  const int wm = wv >> 1, wn = wv & 1;
  const int total = meta[129];
  const int rA = wv * 16 + (lane >> 2);
  // swizzle: physical chunk c holds global chunk (c - (r>>1))&3; r>>1 == lane>>3 (mod 4).
  const int cb = ((((lane & 3) - ((lane >> 3) & 3)) & 3)) * 16;
  char* dA0 = (char*)ldsA + wv * 1024 + lane * 16;
  char* dA1 = dA0 + 4096;
  char* dB00 = (char*)ldsB0 + wv * 1024 + lane * 16;
  char* dB01 = dB00 + 4096;
  char* dB10 = (char*)ldsB1 + wv * 1024 + lane * 16;
  char* dB11 = dB10 + 4096;
  const int ml = lane & 15, q = lane >> 4;
  const int pq = (q + (ml >> 1)) & 3;  // physical chunk for logical k-chunk q
  const unsigned short* pA = &ldsA[(wm * 64 + ml) * 32 + pq * 8];
  const unsigned short* pB0 = &ldsB0[(wn * 64 + ml) * 32 + pq * 8];
  const unsigned short* pB1 = &ldsB1[(wn * 64 + ml) * 32 + pq * 8];

  for (int w = blockIdx.x; w < total; w += gridDim.x) {
    int b = 0;
    while (b < 31 && w >= meta[97 + b + 1]) ++b;
    const int local = w - meta[97 + b];
    const int mt = local >> 3, nt = local & 7;
    const int e = b >> 1;
    const int slot0 = meta[64 + b] + mt * 128;
    const int n0 = nt * 128;
    const int tok0 = slot_token[slot0 + rA];
    const int tok1 = slot_token[slot0 + 64 + rA];
    const char* gA0 = (const char*)(xb + (size_t)tok0 * 512) + cb;
    const char* gA1 = (const char*)(xb + (size_t)tok1 * 512) + cb;
    const char* gB00 = (const char*)(w0t + ((size_t)e * 1024 + n0 + rA) * 512) + cb;
    const char* gB01 = gB00 + 65536;
    const char* gB10 = (const char*)(w1t + ((size_t)e * 1024 + n0 + rA) * 512) + cb;
    const char* gB11 = gB10 + 65536;
    floatx4 acc0[4][4], acc1[4][4];
#pragma unroll
    for (int i = 0; i < 4; ++i)
#pragma unroll
      for (int j = 0; j < 4; ++j) {
        acc0[i][j] = (floatx4){0.f, 0.f, 0.f, 0.f};
        acc1[i][j] = (floatx4){0.f, 0.f, 0.f, 0.f};
      }
#pragma unroll 1
    for (int kt = 0; kt < 16; ++kt) {
      __syncthreads();
      const int ko = kt * 64;
      async16(dA0, gA0 + ko); async16(dA1, gA1 + ko);
      async16(dB00, gB00 + ko); async16(dB01, gB01 + ko);
      async16(dB10, gB10 + ko); async16(dB11, gB11 + ko);
      __syncthreads();
      bf16x8 aV[4], b0V[4], b1V[4];
#pragma unroll
      for (int mi = 0; mi < 4; ++mi) aV[mi] = *(const bf16x8*)(pA + mi * 512);
#pragma unroll
      for (int ni = 0; ni < 4; ++ni) {
        b0V[ni] = *(const bf16x8*)(pB0 + ni * 512);
        b1V[ni] = *(const bf16x8*)(pB1 + ni * 512);
      }
#pragma unroll
      for (int mi = 0; mi < 4; ++mi)
#pragma unroll
        for (int ni = 0; ni < 4; ++ni) {
          acc0[mi][ni] = __builtin_amdgcn_mfma_f32_16x16x32_bf16(aV[mi], b0V[ni], acc0[mi][ni], 0, 0, 0);
          acc1[mi][ni] = __builtin_amdgcn_mfma_f32_16x16x32_bf16(aV[mi], b1V[ni], acc1[mi][ni], 0, 0, 0);
        }
    }
    const int rb = slot0 + wm * 64 + (lane >> 4) * 4;
    const int cbase = n0 + wn * 64 + ml;
#pragma unroll
    for (int mi = 0; mi < 4; ++mi)
#pragma unroll
      for (int ni = 0; ni < 4; ++ni) {
#pragma unroll
        for (int r = 0; r < 4; ++r) {
          const float h0 = acc0[mi][ni][r];
          const float hv = h0 * acc1[mi][ni][r] / (1.f + __expf(-h0));
          hb[(size_t)(rb + mi * 16 + r) * 1024 + cbase + ni * 16] = f2bf(hv);
        }
      }
  }
}

// GEMM2: out[tok] (+)= w_slot * (hb[slot] @ wo[e]); kSel=0 store, kSel=1 add. Swizzled LDS.
__global__ __launch_bounds__(256, 2) void gemm2_kernel(
    const unsigned short* __restrict__ hb, const unsigned short* __restrict__ wot,
    float* __restrict__ out, const int* __restrict__ slot_token,
    const float* __restrict__ slot_weight, const int* __restrict__ meta, const int kSel) {
  __shared__ __align__(16) unsigned short ldsA[128 * 32];
  __shared__ __align__(16) unsigned short ldsB[128 * 32];
  const int tid = threadIdx.x, lane = tid & 63, wv = tid >> 6;
  const int wm = wv >> 1, wn = wv & 1;
  const int baseOff = kSel ? 147 : 130;
  const int total = meta[baseOff + 16];
  const int rA = wv * 16 + (lane >> 2);
  const int cb = ((((lane & 3) - ((lane >> 3) & 3)) & 3)) * 16;
  char* dA0 = (char*)ldsA + wv * 1024 + lane * 16;
  char* dA1 = dA0 + 4096;
  char* dB0 = (char*)ldsB + wv * 1024 + lane * 16;
  char* dB1 = dB0 + 4096;
  const int ml = lane & 15, q = lane >> 4;
  const int pq = (q + (ml >> 1)) & 3;
  const unsigned short* pA = &ldsA[(wm * 64 + ml) * 32 + pq * 8];
  const unsigned short* pB = &ldsB[(wn * 64 + ml) * 32 + pq * 8];

  for (int w = blockIdx.x; w < total; w += gridDim.x) {
    int i = 0;
    while (i < 15 && w >= meta[baseOff + i + 1]) ++i;
    const int b = 2 * i + kSel, e = i;
    const int local = w - meta[baseOff + i];
    const int mt = local >> 2, nt = local & 3;
    const int slot0 = meta[64 + b] + mt * 128;
    const int n0 = nt * 128;
    const int bend = meta[64 + b] + meta[b];
    const char* gA0 = (const char*)(hb + (size_t)(slot0 + rA) * 1024) + cb;
    const char* gA1 = gA0 + 64 * 2048;
    const char* gB0 = (const char*)(wot + ((size_t)e * 512 + n0 + rA) * 1024) + cb;
    const char* gB1 = gB0 + 64 * 2048;
    floatx4 acc[4][4];
#pragma unroll
    for (int a = 0; a < 4; ++a)
#pragma unroll
      for (int c = 0; c < 4; ++c) acc[a][c] = (floatx4){0.f, 0.f, 0.f, 0.f};
#pragma unroll 1
    for (int kt = 0; kt < 32; ++kt) {
      __syncthreads();
      const int ko = kt * 64;
      async16(dA0, gA0 + ko); async16(dA1, gA1 + ko);
      async16(dB0, gB0 + ko); async16(dB1, gB1 + ko);
      __syncthreads();
      bf16x8 aV[4], bV[4];
#pragma unroll
      for (int mi = 0; mi < 4; ++mi) aV[mi] = *(const bf16x8*)(pA + mi * 512);
#pragma unroll
      for (int ni = 0; ni < 4; ++ni) bV[ni] = *(const bf16x8*)(pB + ni * 512);
#pragma unroll
      for (int mi = 0; mi < 4; ++mi)
#pragma unroll
        for (int ni = 0; ni < 4; ++ni)
          acc[mi][ni] = __builtin_amdgcn_mfma_f32_16x16x32_bf16(aV[mi], bV[ni], acc[mi][ni], 0, 0, 0);
    }
    const int rb = slot0 + wm * 64 + (lane >> 4) * 4;
    const int cbase = n0 + wn * 64 + ml;
#pragma unroll
    for (int mi = 0; mi < 4; ++mi) {
#pragma unroll
      for (int r = 0; r < 4; ++r) {
        const int sl = rb + mi * 16 + r;
        if (sl < bend) {
          const int tk = slot_token[sl];
          const float wt = slot_weight[sl];
#pragma unroll
          for (int ni = 0; ni < 4; ++ni) {
            const size_t oidx = (size_t)tk * 512 + cbase + ni * 16;
            float v = acc[mi][ni][r] * wt;
            if (kSel) v += out[oidx];
            out[oidx] = v;
          }
        }
      }
    }
  }
}

extern "C" void kernel_launch(void* const* d_in, const int* in_sizes, int n_in,
                              void* d_out, int out_size, void* d_ws, size_t ws_size,
                              hipStream_t stream) {
  const float* x = (const float*)d_in[0];
  const float* wg = (const float*)d_in[1];
  const float* w0 = (const float*)d_in[2];
  const float* w1 = (const float*)d_in[3];
  const float* wo = (const float*)d_in[4];
  float* out = (float*)d_out;
  char* ws = (char*)d_ws;
  if (ws_size < (size_t)WS_NEED) return;  // need ~217 MB scratch
  unsigned short* xb = (unsigned short*)(ws + O_XB);
  unsigned short* w0t = (unsigned short*)(ws + O_W0T);
  unsigned short* w1t = (unsigned short*)(ws + O_W1T);
  unsigned short* wot = (unsigned short*)(ws + O_WOT);
  unsigned short* hb = (unsigned short*)(ws + O_HB);
  int* slot_token = (int*)(ws + O_STOK);
  float* slot_weight = (float*)(ws + O_SW);
  int2* tok_e = (int2*)(ws + O_TE);
  float2* tok_w = (float2*)(ws + O_TW);
  int* meta = (int*)(ws + O_META);

  init_kernel<<<(CAP + 255) / 256, 256, 0, stream>>>(slot_token, slot_weight, meta);
  convert_x_kernel<<<NTOK * 512 / 2048, 256, 0, stream>>>(x, xb);
  gating_kernel<<<512, 256, 0, stream>>>(x, wg, meta, tok_e, tok_w);
  offsets_kernel<<<1, 1, 0, stream>>>(meta);
  scatter_kernel<<<NTOK / 256, 256, 0, stream>>>(tok_e, tok_w, slot_token, slot_weight, meta);
  transpose_kernel<<<dim3(16, 16, 48), 256, 0, stream>>>(w0, w1, wo, w0t, w1t, wot);
  gemm1_kernel<<<4096, 256, 0, stream>>>(xb, w0t, w1t, hb, slot_token, meta);
  gemm2_kernel<<<1024, 256, 0, stream>>>(hb, wot, out, slot_token, slot_weight, meta, 0);
  gemm2_kernel<<<1024, 256, 0, stream>>>(hb, wot, out, slot_token, slot_weight, meta, 1);
}